// Round 1
// baseline (5563.776 us; speedup 1.0000x reference)
//
#include <hip/hip_runtime.h>
#include <math.h>

// Decoder_910533066914 — Bahdanau-attention LSTM decoder, fp32 baseline.
// Attention weights are h-independent (tanh(hW1+b1)·Va is constant over s and
// cancels in softmax_s) -> context/attention computed once; recurrence is only
// z = pre + h@Wh -> gates; logits done as one batched GEMM at the end.

constexpr int B = 32, T = 64, S = 64, D = 1024, A = 512, E = 256, L = 1024, V = 12000;
constexpr int G = 4 * L; // 4096

constexpr size_t N_PROBS = (size_t)B * T * V; // 24,576,000

// ---------------- precompute kernels ----------------

// v2[d] = sum_a W2[d,a] * Va[a]   (one wave per d)
__global__ void k_v2(const float* __restrict__ W2, const float* __restrict__ Va,
                     float* __restrict__ v2) {
  int gw = (blockIdx.x * blockDim.x + threadIdx.x) >> 6;
  int lane = threadIdx.x & 63;
  if (gw >= D) return;
  float acc = 0.f;
  for (int a = lane; a < A; a += 64) acc += W2[(size_t)gw * A + a] * Va[a];
  #pragma unroll
  for (int off = 32; off; off >>= 1) acc += __shfl_down(acc, off);
  if (lane == 0) v2[gw] = acc;
}

// score[b,s] = sum_d options[b,s,d] * v2[d]   (one wave per (b,s) row)
__global__ void k_score(const float* __restrict__ options, const float* __restrict__ v2,
                        float* __restrict__ w) {
  int row = (blockIdx.x * blockDim.x + threadIdx.x) >> 6;
  int lane = threadIdx.x & 63;
  if (row >= B * S) return;
  const float* orow = options + (size_t)row * D;
  float acc = 0.f;
  for (int d = lane; d < D; d += 64) acc += orow[d] * v2[d];
  #pragma unroll
  for (int off = 32; off; off >>= 1) acc += __shfl_down(acc, off);
  if (lane == 0) w[row] = acc;
}

// softmax over s (64 lanes == S); writes w in place and the attention output
__global__ void k_attn_softmax(float* __restrict__ w, float* __restrict__ oattn) {
  int b = (blockIdx.x * blockDim.x + threadIdx.x) >> 6;
  int lane = threadIdx.x & 63;
  if (b >= B) return;
  float v = w[b * S + lane];
  float m = v;
  #pragma unroll
  for (int off = 32; off; off >>= 1) m = fmaxf(m, __shfl_xor(m, off));
  float e = expf(v - m);
  float s = e;
  #pragma unroll
  for (int off = 32; off; off >>= 1) s += __shfl_xor(s, off);
  float res = e / s;
  w[b * S + lane] = res;
  oattn[b * S + lane] = res;
}

// context[b,d] = sum_s w[b,s] * options[b,s,d]
__global__ void k_context(const float* __restrict__ options, const float* __restrict__ w,
                          float* __restrict__ ctx) {
  int i = blockIdx.x * 256 + threadIdx.x; // b*D + d
  int b = i >> 10, d = i & 1023;
  float acc = 0.f;
  for (int s = 0; s < S; ++s) acc += w[b * S + s] * options[((size_t)(b * S + s) << 10) + d];
  ctx[i] = acc;
}

// cx[b,j] = bl[j] + sum_d ctx[b,d] * Wx[d,j]   (grid 64 = 16 jtiles x 4 bgroups)
__global__ void k_cx(const float* __restrict__ ctx, const float* __restrict__ Wx,
                     const float* __restrict__ bl, float* __restrict__ cx) {
  int jt = blockIdx.x & 15;
  int bg = blockIdx.x >> 4;
  int j = jt * 256 + threadIdx.x;
  int b0 = bg * 8;
  float acc[8];
  float bv = bl[j];
  #pragma unroll
  for (int bb = 0; bb < 8; ++bb) acc[bb] = bv;
  for (int d = 0; d < D; ++d) {
    float wv = Wx[(size_t)d * G + j];
    #pragma unroll
    for (int bb = 0; bb < 8; ++bb) acc[bb] = fmaf(ctx[(b0 + bb) * D + d], wv, acc[bb]);
  }
  #pragma unroll
  for (int bb = 0; bb < 8; ++bb) cx[(size_t)(b0 + bb) * G + j] = acc[bb];
}

// pre[r,j] = cx[b,j] + sum_e emb[tok(r),e] * Wx[D+e, j]   (r = b*T + t)
// grid 2048 = 16 jtiles x 128 rowtiles(16 rows, all same b)
__global__ void k_pre(const int* __restrict__ targets, const float* __restrict__ emb,
                      const float* __restrict__ Wx, const float* __restrict__ cx,
                      float* __restrict__ pre) {
  __shared__ float se[16][256]; // 16 KB
  int jt = blockIdx.x & 15;
  int rt = blockIdx.x >> 4;
  int tid = threadIdx.x;
  int j = jt * 256 + tid;
  int r0 = rt * 16;
  #pragma unroll
  for (int r = 0; r < 16; ++r) {
    int tok = targets[r0 + r];
    se[r][tid] = emb[(size_t)tok * E + tid];
  }
  __syncthreads();
  float acc[16];
  #pragma unroll
  for (int r = 0; r < 16; ++r) acc[r] = 0.f;
  for (int e = 0; e < E; ++e) {
    float wx = Wx[(size_t)(D + e) * G + j];
    #pragma unroll
    for (int r = 0; r < 16; ++r) acc[r] = fmaf(se[r][e], wx, acc[r]);
  }
  int b = r0 >> 6;
  float cxv = cx[(size_t)b * G + j];
  #pragma unroll
  for (int r = 0; r < 16; ++r) pre[(size_t)(r0 + r) * G + j] = acc[r] + cxv;
}

__global__ void k_copy(const float* __restrict__ src, float* __restrict__ dst, int n) {
  int i = blockIdx.x * blockDim.x + threadIdx.x;
  if (i < n) dst[i] = src[i];
}

// ---------------- recurrence step ----------------
// grid 64 = 16 lidx-tiles(64) x 4 bgroups(8 b); block 512 = 64 lidx x 8 lchunks(128 l)
// z[b, g*L + j0] = pre[...] + sum_l h[b,l] * Wh[l, g*L + j0]; then LSTM gates.
__global__ __launch_bounds__(512) void k_step(
    const float* __restrict__ Wh, const float* __restrict__ pre,
    const float* __restrict__ hin, float* __restrict__ cstate,
    float* __restrict__ hout, int t) {
  __shared__ float red[4][32][64]; // 32 KB  [lc][g*8+bb][lidx]
  const int lt = blockIdx.x & 15;
  const int bg = blockIdx.x >> 4;
  const int lidx = threadIdx.x & 63;
  const int lc = threadIdx.x >> 6; // 0..7
  const int j0 = lt * 64 + lidx;
  const int b0 = bg * 8;
  float acc[4][8];
  #pragma unroll
  for (int g = 0; g < 4; ++g)
    #pragma unroll
    for (int bb = 0; bb < 8; ++bb) acc[g][bb] = 0.f;
  const int l0 = lc * 128;
  for (int l = l0; l < l0 + 128; ++l) {
    float hv[8];
    #pragma unroll
    for (int bb = 0; bb < 8; ++bb) hv[bb] = hin[((b0 + bb) << 10) + l];
    #pragma unroll
    for (int g = 0; g < 4; ++g) {
      float wv = Wh[(size_t)l * G + g * L + j0];
      #pragma unroll
      for (int bb = 0; bb < 8; ++bb) acc[g][bb] = fmaf(hv[bb], wv, acc[g][bb]);
    }
  }
  // two-level reduce over the 8 l-chunks using 32 KB of LDS
  if (lc >= 4) {
    #pragma unroll
    for (int g = 0; g < 4; ++g)
      #pragma unroll
      for (int bb = 0; bb < 8; ++bb) red[lc - 4][g * 8 + bb][lidx] = acc[g][bb];
  }
  __syncthreads();
  if (lc < 4) {
    #pragma unroll
    for (int g = 0; g < 4; ++g)
      #pragma unroll
      for (int bb = 0; bb < 8; ++bb) {
        acc[g][bb] += red[lc][g * 8 + bb][lidx];
        red[lc][g * 8 + bb][lidx] = acc[g][bb];
      }
  }
  __syncthreads();
  // gate phase: 512 units = 8 b x 64 lidx, one per thread
  {
    const int u = threadIdx.x;
    const int li = u & 63, bb = u >> 6;
    const int b = b0 + bb, jj = lt * 64 + li;
    float z[4];
    #pragma unroll
    for (int g = 0; g < 4; ++g) {
      float s = 0.f;
      #pragma unroll
      for (int k = 0; k < 4; ++k) s += red[k][g * 8 + bb][li];
      z[g] = s;
    }
    const float* pr = pre + ((size_t)(b * T + t)) * G;
    float zi = z[0] + pr[0 * L + jj];
    float zf = z[1] + pr[1 * L + jj];
    float zg = z[2] + pr[2 * L + jj];
    float zo = z[3] + pr[3 * L + jj];
    float si = 1.f / (1.f + expf(-zi));
    float sf = 1.f / (1.f + expf(-zf));
    float tg = tanhf(zg);
    float so = 1.f / (1.f + expf(-zo));
    float cn = sf * cstate[b * L + jj] + si * tg;
    float hn = so * tanhf(cn);
    cstate[b * L + jj] = cn;
    hout[b * L + jj] = hn;
  }
}

// ---------------- output GEMM + softmax ----------------
// logits[r, v] = bd[v] + sum_l Hb[t,b,l] * Wd[l,v]  written into d_out probs region
// grid = 47 vtiles x 32 rowtiles(64 rows); block 256 (one v per thread)
__global__ __launch_bounds__(256) void k_logits(
    const float* __restrict__ Hb, const float* __restrict__ Wd,
    const float* __restrict__ bd, float* __restrict__ out) {
  __shared__ float sh[64][64]; // 16 KB
  const int vt = blockIdx.x % 47;
  const int rt = blockIdx.x / 47;
  const int tid = threadIdx.x;
  const int v = vt * 256 + tid;
  const bool valid = v < V;
  const int vc = valid ? v : (V - 1);
  const int r0 = rt * 64;
  float acc[64];
  #pragma unroll
  for (int i = 0; i < 64; ++i) acc[i] = 0.f;
  for (int ch = 0; ch < 16; ++ch) {
    const int lc0 = ch * 64;
    __syncthreads();
    #pragma unroll
    for (int k = 0; k < 16; ++k) {
      int idx = tid + k * 256;
      int i = idx >> 6, l = idx & 63;
      int r = r0 + i;
      int b = r >> 6, tt = r & 63;
      sh[i][l] = Hb[(((size_t)tt * B + b) << 10) + lc0 + l];
    }
    __syncthreads();
    for (int l = 0; l < 64; ++l) {
      float wd = Wd[(size_t)(lc0 + l) * V + vc];
      #pragma unroll
      for (int i = 0; i < 64; ++i) acc[i] = fmaf(sh[i][l], wd, acc[i]);
    }
  }
  if (valid) {
    float bv = bd[v];
    for (int i = 0; i < 64; ++i) out[(size_t)(r0 + i) * V + v] = acc[i] + bv;
  }
}

// in-place row softmax over V=12000; one block per row, row staged in LDS
__global__ __launch_bounds__(256) void k_softmax(float* __restrict__ logits) {
  __shared__ float srow[V];   // 48000 B
  __shared__ float sred[4];
  int r = blockIdx.x;
  float* row = logits + (size_t)r * V;
  int tid = threadIdx.x;
  float m = -3.4e38f;
  for (int v = tid; v < V; v += 256) {
    float x = row[v];
    srow[v] = x;
    m = fmaxf(m, x);
  }
  #pragma unroll
  for (int off = 32; off; off >>= 1) m = fmaxf(m, __shfl_xor(m, off));
  if ((tid & 63) == 0) sred[tid >> 6] = m;
  __syncthreads();
  float M = fmaxf(fmaxf(sred[0], sred[1]), fmaxf(sred[2], sred[3]));
  float s = 0.f;
  for (int v = tid; v < V; v += 256) {
    float e = __expf(srow[v] - M);
    srow[v] = e;
    s += e;
  }
  #pragma unroll
  for (int off = 32; off; off >>= 1) s += __shfl_xor(s, off);
  __syncthreads(); // everyone done reading sred (max) before overwrite
  if ((tid & 63) == 0) sred[tid >> 6] = s;
  __syncthreads();
  float inv = 1.f / (sred[0] + sred[1] + sred[2] + sred[3]);
  for (int v = tid; v < V; v += 256) row[v] = srow[v] * inv;
}

__global__ void k_finalize(const float* __restrict__ hfin, const float* __restrict__ cfin,
                           float* __restrict__ oh, float* __restrict__ oc) {
  int i = blockIdx.x * blockDim.x + threadIdx.x;
  if (i < B * L) {
    oh[i] = hfin[i];
    oc[i] = cfin[i];
  }
}

// ---------------- launch ----------------

extern "C" void kernel_launch(void* const* d_in, const int* in_sizes, int n_in,
                              void* d_out, int out_size, void* d_ws, size_t ws_size,
                              hipStream_t stream) {
  const int*   targets = (const int*)d_in[0];
  const float* options = (const float*)d_in[1];
  const float* h0      = (const float*)d_in[2];
  const float* c0      = (const float*)d_in[3];
  const float* emb     = (const float*)d_in[4];
  // d_in[5] W1, d_in[6] b1, d_in[8] b2, d_in[9] Va (b2/W1/b1/bVa cancel in softmax)
  const float* W2      = (const float*)d_in[7];
  const float* Va      = (const float*)d_in[9];
  const float* Wx      = (const float*)d_in[11];
  const float* Wh      = (const float*)d_in[12];
  const float* bl      = (const float*)d_in[13];
  const float* Wd      = (const float*)d_in[14];
  const float* bd      = (const float*)d_in[15];

  float* out      = (float*)d_out;
  float* out_h    = out + N_PROBS;
  float* out_c    = out_h + (size_t)B * L;
  float* out_attn = out_c + (size_t)B * L;

  // workspace layout (floats), total ~10.7M floats = 42.9 MB
  float* ws  = (float*)d_ws;
  float* v2  = ws;                             // 1024
  float* wat = ws + 1024;                      // 2048 (B*S)
  float* ctx = ws + 3072;                      // 32768 (B*D)
  float* cx  = ctx + (size_t)B * D;            // 131072 (B*G)
  float* pre = cx + (size_t)B * G;             // 8,388,608 (B*T*G)
  float* Hb  = pre + (size_t)B * T * G;        // 2,097,152 (T*B*L)
  float* cst = Hb + (size_t)T * B * L;         // 32768 (B*L)

  k_v2<<<256, 256, 0, stream>>>(W2, Va, v2);
  k_score<<<512, 256, 0, stream>>>(options, v2, wat);
  k_attn_softmax<<<8, 256, 0, stream>>>(wat, out_attn);
  k_context<<<128, 256, 0, stream>>>(options, wat, ctx);
  k_cx<<<64, 256, 0, stream>>>(ctx, Wx, bl, cx);
  k_pre<<<2048, 256, 0, stream>>>(targets, emb, Wx, cx, pre);
  k_copy<<<128, 256, 0, stream>>>(c0, cst, B * L);

  for (int t = 0; t < T; ++t) {
    const float* hin = (t == 0) ? h0 : (Hb + (size_t)(t - 1) * B * L);
    k_step<<<64, 512, 0, stream>>>(Wh, pre, hin, cst, Hb + (size_t)t * B * L, t);
  }

  k_logits<<<47 * 32, 256, 0, stream>>>(Hb, Wd, bd, out);
  k_softmax<<<B * T, 256, 0, stream>>>(out);
  k_finalize<<<128, 256, 0, stream>>>(Hb + (size_t)(T - 1) * B * L, cst, out_h, out_c);
}

// Round 2
// 2138.011 us; speedup vs baseline: 2.6023x; 2.6023x over previous
//
#include <hip/hip_runtime.h>
#include <math.h>

// Decoder_910533066914 — R2: MFMA bf16 logits GEMM + restructured recurrence.
// Attention is h-independent (tanh(hW1+b1)·Va cancels over s in softmax) ->
// context once; recurrence z = pre + h@Wh (fp32, h kept transposed [l][b]);
// logits = Hb16[2048x1024]bf16 @ Wdt[12032x1024]bf16 via mfma_f32_16x16x32_bf16.

typedef __bf16 bf16;
typedef __attribute__((ext_vector_type(8))) __bf16 bf16x8;
typedef __attribute__((ext_vector_type(4))) float f32x4;

constexpr int B = 32, T = 64, S = 64, D = 1024, A = 512, E = 256, L = 1024, V = 12000;
constexpr int G = 4096;            // 4*L
constexpr int NP = 12032;          // padded V (94*128)
constexpr size_t N_PROBS = (size_t)B * T * V;

__device__ inline void load_lds16(const void* g, void* l) {
  __builtin_amdgcn_global_load_lds(
      (const __attribute__((address_space(1))) unsigned int*)g,
      (__attribute__((address_space(3))) unsigned int*)l, 16, 0, 0);
}

// ---------------- precompute (attention, unchanged math) ----------------

__global__ void k_v2(const float* __restrict__ W2, const float* __restrict__ Va,
                     float* __restrict__ v2) {
  int gw = (blockIdx.x * blockDim.x + threadIdx.x) >> 6;
  int lane = threadIdx.x & 63;
  if (gw >= D) return;
  float acc = 0.f;
  for (int a = lane; a < A; a += 64) acc += W2[(size_t)gw * A + a] * Va[a];
  #pragma unroll
  for (int off = 32; off; off >>= 1) acc += __shfl_down(acc, off);
  if (lane == 0) v2[gw] = acc;
}

__global__ void k_score(const float* __restrict__ options, const float* __restrict__ v2,
                        float* __restrict__ w) {
  int row = (blockIdx.x * blockDim.x + threadIdx.x) >> 6;
  int lane = threadIdx.x & 63;
  if (row >= B * S) return;
  const float* orow = options + (size_t)row * D;
  float acc = 0.f;
  for (int d = lane; d < D; d += 64) acc += orow[d] * v2[d];
  #pragma unroll
  for (int off = 32; off; off >>= 1) acc += __shfl_down(acc, off);
  if (lane == 0) w[row] = acc;
}

__global__ void k_attn_softmax(float* __restrict__ w, float* __restrict__ oattn) {
  int b = (blockIdx.x * blockDim.x + threadIdx.x) >> 6;
  int lane = threadIdx.x & 63;
  if (b >= B) return;
  float v = w[b * S + lane];
  float m = v;
  #pragma unroll
  for (int off = 32; off; off >>= 1) m = fmaxf(m, __shfl_xor(m, off));
  float e = expf(v - m);
  float s = e;
  #pragma unroll
  for (int off = 32; off; off >>= 1) s += __shfl_xor(s, off);
  float res = e / s;
  w[b * S + lane] = res;
  oattn[b * S + lane] = res;
}

__global__ void k_context(const float* __restrict__ options, const float* __restrict__ w,
                          float* __restrict__ ctx) {
  int i = blockIdx.x * 256 + threadIdx.x; // b*D + d
  int b = i >> 10;
  float acc = 0.f;
  for (int s = 0; s < S; ++s)
    acc += w[b * S + s] * options[((size_t)(b * S + s) << 10) + (i & 1023)];
  ctx[i] = acc;
}

__global__ void k_cx(const float* __restrict__ ctx, const float* __restrict__ Wx,
                     const float* __restrict__ bl, float* __restrict__ cx) {
  int jt = blockIdx.x & 15;
  int bg = blockIdx.x >> 4;
  int j = jt * 256 + threadIdx.x;
  int b0 = bg * 8;
  float acc[8];
  float bv = bl[j];
  #pragma unroll
  for (int bb = 0; bb < 8; ++bb) acc[bb] = bv;
  for (int d = 0; d < D; ++d) {
    float wv = Wx[(size_t)d * G + j];
    #pragma unroll
    for (int bb = 0; bb < 8; ++bb) acc[bb] = fmaf(ctx[(b0 + bb) * D + d], wv, acc[bb]);
  }
  #pragma unroll
  for (int bb = 0; bb < 8; ++bb) cx[(size_t)(b0 + bb) * G + j] = acc[bb];
}

__global__ void k_pre(const int* __restrict__ targets, const float* __restrict__ emb,
                      const float* __restrict__ Wx, const float* __restrict__ cx,
                      float* __restrict__ pre) {
  __shared__ float se[16][256];
  int jt = blockIdx.x & 15;
  int rt = blockIdx.x >> 4;
  int tid = threadIdx.x;
  int j = jt * 256 + tid;
  int r0 = rt * 16;
  #pragma unroll
  for (int r = 0; r < 16; ++r) {
    int tok = targets[r0 + r];
    se[r][tid] = emb[(size_t)tok * E + tid];
  }
  __syncthreads();
  float acc[16];
  #pragma unroll
  for (int r = 0; r < 16; ++r) acc[r] = 0.f;
  for (int e = 0; e < E; ++e) {
    float wx = Wx[(size_t)(D + e) * G + j];
    #pragma unroll
    for (int r = 0; r < 16; ++r) acc[r] = fmaf(se[r][e], wx, acc[r]);
  }
  int b = r0 >> 6;
  float cxv = cx[(size_t)b * G + j];
  #pragma unroll
  for (int r = 0; r < 16; ++r) pre[(size_t)(r0 + r) * G + j] = acc[r] + cxv;
}

__global__ void k_copy(const float* __restrict__ src, float* __restrict__ dst, int n) {
  int i = blockIdx.x * blockDim.x + threadIdx.x;
  if (i < n) dst[i] = src[i];
}

// ht[l*32 + b] = h0[b*1024 + l]
__global__ void k_ht0(const float* __restrict__ h0, float* __restrict__ ht) {
  int i = blockIdx.x * 256 + threadIdx.x;
  int l = i >> 5, b = i & 31;
  ht[i] = h0[b * 1024 + l];
}

// ---------------- recurrence ----------------
// grid 512 = 256 jb x 2 bh. Block 256 = 16 cols(4 jj x 4 gates) x 16 lchunks(64 l).
// z[b, g*1024+jj] = pre + sum_l ht[l][b] * Wh[l][g*1024+jj]; gates -> ct, ht', Hb16.
__global__ __launch_bounds__(256) void k_step2(
    const float* __restrict__ Wh, const float* __restrict__ pre,
    const float* __restrict__ htin, float* __restrict__ htout,
    float* __restrict__ cstate, bf16* __restrict__ Hb16, int t) {
  __shared__ float red[16 * 16 * 17]; // [lc][col][b] padded, 17408 B
  const int bid = blockIdx.x;
  const int jb = bid >> 1, bh = bid & 1;
  const int jj0 = jb * 4;
  const int tid = threadIdx.x;
  const int col = tid & 15, lc = tid >> 4;
  const int g = col >> 2, jjo = col & 3;
  const int wcol = g * 1024 + jj0 + jjo;
  const float* hb = htin + bh * 16;

  float acc[16];
  #pragma unroll
  for (int i = 0; i < 16; ++i) acc[i] = 0.f;
  const int l0 = lc * 64;
  for (int l = l0; l < l0 + 64; ++l) {
    float wv = Wh[(size_t)l * G + wcol];
    float hv[16];
    const float4* hp = (const float4*)(hb + l * 32);
    *(float4*)&hv[0]  = hp[0];
    *(float4*)&hv[4]  = hp[1];
    *(float4*)&hv[8]  = hp[2];
    *(float4*)&hv[12] = hp[3];
    #pragma unroll
    for (int b = 0; b < 16; ++b) acc[b] = fmaf(hv[b], wv, acc[b]);
  }
  #pragma unroll
  for (int b = 0; b < 16; ++b) red[(lc * 16 + col) * 17 + b] = acc[b];
  __syncthreads();

  if (tid < 64) {
    const int b = tid & 15, jo = tid >> 4;
    const int bglob = bh * 16 + b;
    const int jj = jj0 + jo;
    float z[4];
    #pragma unroll
    for (int gg = 0; gg < 4; ++gg) {
      float s = 0.f;
      #pragma unroll
      for (int k = 0; k < 16; ++k) s += red[(k * 16 + gg * 4 + jo) * 17 + b];
      z[gg] = s;
    }
    const float* pr = pre + (size_t)(bglob * 64 + t) * G;
    float zi = z[0] + pr[jj];
    float zf = z[1] + pr[1024 + jj];
    float zg = z[2] + pr[2048 + jj];
    float zo = z[3] + pr[3072 + jj];
    float si = 1.f / (1.f + expf(-zi));
    float sf = 1.f / (1.f + expf(-zf));
    float tg = tanhf(zg);
    float so = 1.f / (1.f + expf(-zo));
    const int ci = bglob * 1024 + jj;
    float cn = sf * cstate[ci] + si * tg;
    float hn = so * tanhf(cn);
    cstate[ci] = cn;
    htout[jj * 32 + bglob] = hn;
    Hb16[(size_t)(bglob * 64 + t) * 1024 + jj] = (bf16)hn;
  }
}

// ---------------- Wd -> Wdt bf16 transpose (padded to NP rows) ----------------
__global__ __launch_bounds__(256) void k_wdt(const float* __restrict__ Wd,
                                             bf16* __restrict__ Wdt) {
  __shared__ float s[64][65];
  const int lt = blockIdx.x & 15;       // 16 l-tiles
  const int vt = blockIdx.x >> 4;       // 188 v-tiles
  const int l0 = lt * 64, v0 = vt * 64;
  const int tid = threadIdx.x;
  const int lv = tid & 63;
  #pragma unroll
  for (int k = 0; k < 16; ++k) {
    int ll = k * 4 + (tid >> 6);
    int v = v0 + lv;
    s[ll][lv] = (v < V) ? Wd[(size_t)(l0 + ll) * V + v] : 0.f;
  }
  __syncthreads();
  const int vv = tid >> 2, lq = tid & 3;
  bf16x8 o0, o1;
  #pragma unroll
  for (int j = 0; j < 8; ++j) {
    o0[j] = (bf16)s[lq * 16 + j][vv];
    o1[j] = (bf16)s[lq * 16 + 8 + j][vv];
  }
  bf16* dst = Wdt + (size_t)(v0 + vv) * 1024 + l0 + lq * 16;
  *(bf16x8*)dst = o0;
  *(bf16x8*)(dst + 8) = o1;
}

// ---------------- logits: MFMA bf16 GEMM C[2048 x NP] = A[2048x1024] * Bt^T ----
// 128x128 tile, BK=64, 4 waves (2x2 of 64x64), global_load_lds + XOR swizzle.
__global__ __launch_bounds__(256) void k_logits_mfma(
    const bf16* __restrict__ Ag, const bf16* __restrict__ Btg,
    const float* __restrict__ bd, float* __restrict__ out) {
  __shared__ __align__(16) char lds[32768];
  char* sA = lds;
  char* sB = lds + 16384;
  const int bid = blockIdx.x;
  const int wg = (bid & 7) * 188 + (bid >> 3);   // XCD swizzle, 1504 = 8*188
  const int mt = wg / 94, nt = wg % 94;
  const int m0 = mt * 128, n0 = nt * 128;
  const int tid = threadIdx.x, w = tid >> 6, lane = tid & 63;
  const int wr = w >> 1, wc = w & 1;

  f32x4 acc[4][4];
  #pragma unroll
  for (int i = 0; i < 4; ++i)
    #pragma unroll
    for (int j = 0; j < 4; ++j) acc[i][j] = (f32x4){0.f, 0.f, 0.f, 0.f};

  // staging geometry: 16 chunks of 1KB per tile; chunk c = i*4 + w.
  // LDS linear; global source pre-XOR'd so ds_read applies the same XOR.
  int rowc[4], sloc[4];
  #pragma unroll
  for (int i = 0; i < 4; ++i) {
    int c = i * 4 + w;
    rowc[i] = c * 8 + (lane >> 3);          // tile row 0..127
    sloc[i] = (lane & 7) ^ (rowc[i] & 7);   // source 16B chunk within row
  }

  for (int kk = 0; kk < 16; ++kk) {
    if (kk) __syncthreads();
    const char* ga = (const char*)Ag + kk * 128;
    const char* gb = (const char*)Btg + kk * 128;
    #pragma unroll
    for (int i = 0; i < 4; ++i) {
      int c = i * 4 + w;
      load_lds16(ga + (size_t)(m0 + rowc[i]) * 2048 + sloc[i] * 16, sA + c * 1024);
      load_lds16(gb + (size_t)(n0 + rowc[i]) * 2048 + sloc[i] * 16, sB + c * 1024);
    }
    __syncthreads();
    #pragma unroll
    for (int ks = 0; ks < 2; ++ks) {
      bf16x8 av[4], bv[4];
      #pragma unroll
      for (int f = 0; f < 4; ++f) {
        int ra = wr * 64 + f * 16 + (lane & 15);
        int ca = (ks * 4 + (lane >> 4)) ^ (ra & 7);
        av[f] = *(const bf16x8*)(sA + ra * 128 + ca * 16);
        int rb = wc * 64 + f * 16 + (lane & 15);
        int cb = (ks * 4 + (lane >> 4)) ^ (rb & 7);
        bv[f] = *(const bf16x8*)(sB + rb * 128 + cb * 16);
      }
      #pragma unroll
      for (int fm = 0; fm < 4; ++fm)
        #pragma unroll
        for (int fn = 0; fn < 4; ++fn)
          acc[fm][fn] = __builtin_amdgcn_mfma_f32_16x16x32_bf16(
              av[fm], bv[fn], acc[fm][fn], 0, 0, 0);
    }
  }

  // epilogue: C/D layout col=lane&15, row=(lane>>4)*4+reg (m89-verified)
  const int r0o = m0 + wr * 64 + ((lane >> 4) << 2);
  const int c0o = n0 + wc * 64 + (lane & 15);
  #pragma unroll
  for (int fn = 0; fn < 4; ++fn) {
    int colg = c0o + fn * 16;
    if (colg < V) {
      float bv = bd[colg];
      #pragma unroll
      for (int fm = 0; fm < 4; ++fm) {
        #pragma unroll
        for (int r = 0; r < 4; ++r)
          out[(size_t)(r0o + fm * 16 + r) * V + colg] = acc[fm][fn][r] + bv;
      }
    }
  }
}

// ---------------- row softmax over V (float4) ----------------
__global__ __launch_bounds__(256) void k_softmax(float* __restrict__ logits) {
  __shared__ float srow[V]; // 48000 B
  __shared__ float sred[4];
  float* row = logits + (size_t)blockIdx.x * V;
  const int tid = threadIdx.x;
  const float4* rv = (const float4*)row;
  float4* sv = (float4*)srow;
  float m = -3.4e38f;
  for (int i = tid; i < 3000; i += 256) {
    float4 x = rv[i];
    sv[i] = x;
    m = fmaxf(fmaxf(m, fmaxf(x.x, x.y)), fmaxf(x.z, x.w));
  }
  #pragma unroll
  for (int off = 32; off; off >>= 1) m = fmaxf(m, __shfl_xor(m, off));
  if ((tid & 63) == 0) sred[tid >> 6] = m;
  __syncthreads();
  const float M = fmaxf(fmaxf(sred[0], sred[1]), fmaxf(sred[2], sred[3]));
  float s = 0.f;
  for (int i = tid; i < 3000; i += 256) {
    float4 x = sv[i];
    x.x = __expf(x.x - M); x.y = __expf(x.y - M);
    x.z = __expf(x.z - M); x.w = __expf(x.w - M);
    sv[i] = x;
    s += x.x + x.y + x.z + x.w;
  }
  #pragma unroll
  for (int off = 32; off; off >>= 1) s += __shfl_xor(s, off);
  __syncthreads();
  if ((tid & 63) == 0) sred[tid >> 6] = s;
  __syncthreads();
  const float inv = 1.f / (sred[0] + sred[1] + sred[2] + sred[3]);
  float4* ov = (float4*)row;
  for (int i = tid; i < 3000; i += 256) {
    float4 x = sv[i];
    x.x *= inv; x.y *= inv; x.z *= inv; x.w *= inv;
    ov[i] = x;
  }
}

__global__ void k_finalize(const float* __restrict__ ht0, const float* __restrict__ cst,
                           float* __restrict__ oh, float* __restrict__ oc) {
  int i = blockIdx.x * 256 + threadIdx.x; // b*1024 + l
  if (i < B * L) {
    int b = i >> 10, l = i & 1023;
    oh[i] = ht0[l * 32 + b];
    oc[i] = cst[i];
  }
}

// ---------------- launch ----------------

extern "C" void kernel_launch(void* const* d_in, const int* in_sizes, int n_in,
                              void* d_out, int out_size, void* d_ws, size_t ws_size,
                              hipStream_t stream) {
  const int*   targets = (const int*)d_in[0];
  const float* options = (const float*)d_in[1];
  const float* h0      = (const float*)d_in[2];
  const float* c0      = (const float*)d_in[3];
  const float* emb     = (const float*)d_in[4];
  const float* W2      = (const float*)d_in[7];
  const float* Va      = (const float*)d_in[9];
  const float* Wx      = (const float*)d_in[11];
  const float* Wh      = (const float*)d_in[12];
  const float* bl      = (const float*)d_in[13];
  const float* Wd      = (const float*)d_in[14];
  const float* bd      = (const float*)d_in[15];

  float* out      = (float*)d_out;
  float* out_h    = out + N_PROBS;
  float* out_c    = out_h + (size_t)B * L;
  float* out_attn = out_c + (size_t)B * L;

  // workspace (floats): total ~38.8 MB
  float* ws   = (float*)d_ws;
  float* v2   = ws;                      // 1024
  float* wat  = v2 + 1024;               // 2048
  float* ctx  = wat + 2048;              // 32768
  float* cx   = ctx + 32768;             // 131072
  float* htA  = cx + 131072;             // 32768
  float* htB  = htA + 32768;             // 32768
  float* cst  = htB + 32768;             // 32768
  bf16*  Hb16 = (bf16*)(cst + 32768);    // 2048*1024 bf16 = 1,048,576 floats
  float* pre  = cst + 32768 + 1048576;   // 8,388,608 floats
  bf16*  Wdt  = (bf16*)pre;              // alias: used only after the steps

  k_v2<<<256, 256, 0, stream>>>(W2, Va, v2);
  k_score<<<512, 256, 0, stream>>>(options, v2, wat);
  k_attn_softmax<<<8, 256, 0, stream>>>(wat, out_attn);
  k_context<<<128, 256, 0, stream>>>(options, wat, ctx);
  k_cx<<<64, 256, 0, stream>>>(ctx, Wx, bl, cx);
  k_pre<<<2048, 256, 0, stream>>>(targets, emb, Wx, cx, pre);
  k_ht0<<<128, 256, 0, stream>>>(h0, htA);
  k_copy<<<128, 256, 0, stream>>>(c0, cst, B * L);

  float* hbuf[2] = {htA, htB};
  for (int t = 0; t < T; ++t) {
    k_step2<<<512, 256, 0, stream>>>(Wh, pre, hbuf[t & 1], hbuf[(t + 1) & 1],
                                     cst, Hb16, t);
  }

  k_wdt<<<188 * 16, 256, 0, stream>>>(Wd, Wdt);
  k_logits_mfma<<<1504, 256, 0, stream>>>(Hb16, Wdt, bd, out);
  k_softmax<<<B * T, 256, 0, stream>>>(out);
  k_finalize<<<128, 256, 0, stream>>>(hbuf[0], cst, out_h, out_c);
}

// Round 4
// 761.053 us; speedup vs baseline: 7.3106x; 2.8093x over previous
//
#include <hip/hip_runtime.h>
#include <math.h>

// Decoder_910533066914 — R4: R3 with the pre-buffer allocation bug fixed.
// R3 failure root-cause: pre_hi/pre_lo are [2048][4096] = 16 MB each but were
// allocated 8 MB -> recurrence read garbage. Fix: pre as single fp16 [2048][4096]
// (16 MB, correctly sized). All MFMA math unchanged from R3 (verified against
// the passing k_logits_mfma fragment convention).

typedef __bf16 bf16;
typedef _Float16 fp16;
typedef __attribute__((ext_vector_type(8))) __bf16 bf16x8;
typedef __attribute__((ext_vector_type(4))) float f32x4;

constexpr int B = 32, T = 64, S = 64, D = 1024, A = 512, E = 256, L = 1024, V = 12000;
constexpr int G = 4096;
constexpr size_t N_PROBS = (size_t)B * T * V;

__device__ inline void load_lds16(const void* g, void* l) {
  __builtin_amdgcn_global_load_lds(
      (const __attribute__((address_space(1))) unsigned int*)g,
      (__attribute__((address_space(3))) unsigned int*)l, 16, 0, 0);
}

// ---------------- attention precompute (unchanged, R2-verified) ----------------

__global__ void k_v2(const float* __restrict__ W2, const float* __restrict__ Va,
                     float* __restrict__ v2) {
  int gw = (blockIdx.x * blockDim.x + threadIdx.x) >> 6;
  int lane = threadIdx.x & 63;
  if (gw >= D) return;
  float acc = 0.f;
  for (int a = lane; a < A; a += 64) acc += W2[(size_t)gw * A + a] * Va[a];
  #pragma unroll
  for (int off = 32; off; off >>= 1) acc += __shfl_down(acc, off);
  if (lane == 0) v2[gw] = acc;
}

__global__ void k_score(const float* __restrict__ options, const float* __restrict__ v2,
                        float* __restrict__ w) {
  int row = (blockIdx.x * blockDim.x + threadIdx.x) >> 6;
  int lane = threadIdx.x & 63;
  if (row >= B * S) return;
  const float* orow = options + (size_t)row * D;
  float acc = 0.f;
  for (int d = lane; d < D; d += 64) acc += orow[d] * v2[d];
  #pragma unroll
  for (int off = 32; off; off >>= 1) acc += __shfl_down(acc, off);
  if (lane == 0) w[row] = acc;
}

__global__ void k_attn_softmax(float* __restrict__ w, float* __restrict__ oattn) {
  int b = (blockIdx.x * blockDim.x + threadIdx.x) >> 6;
  int lane = threadIdx.x & 63;
  if (b >= B) return;
  float v = w[b * S + lane];
  float m = v;
  #pragma unroll
  for (int off = 32; off; off >>= 1) m = fmaxf(m, __shfl_xor(m, off));
  float e = expf(v - m);
  float s = e;
  #pragma unroll
  for (int off = 32; off; off >>= 1) s += __shfl_xor(s, off);
  float res = e / s;
  w[b * S + lane] = res;
  oattn[b * S + lane] = res;
}

__global__ void k_context(const float* __restrict__ options, const float* __restrict__ w,
                          float* __restrict__ ctx) {
  int i = blockIdx.x * 256 + threadIdx.x;
  int b = i >> 10;
  float acc = 0.f;
  for (int s = 0; s < S; ++s)
    acc += w[b * S + s] * options[((size_t)(b * S + s) << 10) + (i & 1023)];
  ctx[i] = acc;
}

// ---------------- cx = bl + ctx@Wx1, split-K ----------------
__global__ __launch_bounds__(256) void k_cx_part(
    const float* __restrict__ ctx, const float* __restrict__ Wx,
    float* __restrict__ cxp) {
  const int jt = blockIdx.x & 15;
  const int bg = (blockIdx.x >> 4) & 3;
  const int kc = blockIdx.x >> 6;
  const int j = jt * 256 + threadIdx.x;
  const int b0 = bg * 8, d0 = kc * 128;
  float acc[8];
  #pragma unroll
  for (int bb = 0; bb < 8; ++bb) acc[bb] = 0.f;
  for (int d = 0; d < 128; ++d) {
    float wv = Wx[(size_t)(d0 + d) * G + j];
    #pragma unroll
    for (int bb = 0; bb < 8; ++bb)
      acc[bb] = fmaf(ctx[(b0 + bb) * D + d0 + d], wv, acc[bb]);
  }
  #pragma unroll
  for (int bb = 0; bb < 8; ++bb)
    cxp[((size_t)kc * 32 + b0 + bb) * G + j] = acc[bb];
}

__global__ void k_cx_reduce(const float* __restrict__ cxp, const float* __restrict__ bl,
                            float* __restrict__ cx) {
  int i = blockIdx.x * 256 + threadIdx.x; // 131072
  float s = bl[i & 4095];
  #pragma unroll
  for (int kc = 0; kc < 8; ++kc) s += cxp[(size_t)kc * 131072 + i];
  cx[i] = s;
}

// ---------------- gathers / transposes with hi/lo split ----------------

__global__ void k_eg(const int* __restrict__ targets, const float* __restrict__ emb,
                     bf16* __restrict__ eg_hi, bf16* __restrict__ eg_lo) {
  int r = blockIdx.x, e = threadIdx.x;
  int tok = targets[r];
  float x = emb[(size_t)tok * E + e];
  bf16 hi = (bf16)x;
  eg_hi[(size_t)r * E + e] = hi;
  eg_lo[(size_t)r * E + e] = (bf16)(x - (float)hi);
}

__global__ __launch_bounds__(256) void k_wx2t(const float* __restrict__ Wx,
                                              bf16* __restrict__ t_hi,
                                              bf16* __restrict__ t_lo) {
  __shared__ float s[64][65];
  const int et = blockIdx.x >> 6, jt = blockIdx.x & 63;
  const int e0 = et * 64, j0 = jt * 64;
  const int tid = threadIdx.x;
  const int jj = tid & 63;
  #pragma unroll
  for (int k = 0; k < 16; ++k) {
    int ee = k * 4 + (tid >> 6);
    s[ee][jj] = Wx[(size_t)(D + e0 + ee) * G + j0 + jj];
  }
  __syncthreads();
  const int jc = tid >> 2, eq = tid & 3;
  bf16x8 h0, h1, l0, l1;
  #pragma unroll
  for (int i = 0; i < 8; ++i) {
    float a = s[eq * 16 + i][jc], b = s[eq * 16 + 8 + i][jc];
    bf16 ah = (bf16)a, bh = (bf16)b;
    h0[i] = ah; l0[i] = (bf16)(a - (float)ah);
    h1[i] = bh; l1[i] = (bf16)(b - (float)bh);
  }
  size_t dst = (size_t)(j0 + jc) * E + e0 + eq * 16;
  *(bf16x8*)(t_hi + dst) = h0; *(bf16x8*)(t_hi + dst + 8) = h1;
  *(bf16x8*)(t_lo + dst) = l0; *(bf16x8*)(t_lo + dst + 8) = l1;
}

// Whp[rowp][l] = Wh[l][col], rowp = (jj>>2)*16 + g*4 + (jj&3), col = g*1024+jj.
__global__ __launch_bounds__(256) void k_whp(const float* __restrict__ Wh,
                                             bf16* __restrict__ p_hi,
                                             bf16* __restrict__ p_lo) {
  __shared__ float s[64][65];
  const int lt = blockIdx.x & 15, ct = blockIdx.x >> 4;
  const int l0 = lt * 64, c0 = ct * 64;
  const int tid = threadIdx.x;
  const int cc = tid & 63;
  #pragma unroll
  for (int k = 0; k < 16; ++k) {
    int ll = k * 4 + (tid >> 6);
    s[ll][cc] = Wh[(size_t)(l0 + ll) * G + c0 + cc];
  }
  __syncthreads();
  const int c = tid >> 2, lq = tid & 3;
  const int col = c0 + c, g = col >> 10, jj = col & 1023;
  const int rowp = ((jj >> 2) << 4) + (g << 2) + (jj & 3);
  bf16x8 h0, h1, l0v, l1v;
  #pragma unroll
  for (int i = 0; i < 8; ++i) {
    float a = s[lq * 16 + i][c], b = s[lq * 16 + 8 + i][c];
    bf16 ah = (bf16)a, bh = (bf16)b;
    h0[i] = ah; l0v[i] = (bf16)(a - (float)ah);
    h1[i] = bh; l1v[i] = (bf16)(b - (float)bh);
  }
  size_t dst = (size_t)rowp * L + l0 + lq * 16;
  *(bf16x8*)(p_hi + dst) = h0; *(bf16x8*)(p_hi + dst + 8) = h1;
  *(bf16x8*)(p_lo + dst) = l0v; *(bf16x8*)(p_lo + dst + 8) = l1v;
}

__global__ void k_h0split(const float* __restrict__ h0, const float* __restrict__ c0,
                          bf16* __restrict__ h_hi, bf16* __restrict__ h_lo,
                          float* __restrict__ cst, float* __restrict__ hf32) {
  int i = blockIdx.x * 256 + threadIdx.x;
  float x = h0[i];
  bf16 hi = (bf16)x;
  h_hi[i] = hi;
  h_lo[i] = (bf16)(x - (float)hi);
  hf32[i] = x;
  cst[i] = c0[i];
}

// ---------------- pre = Eg@Wx2t^T + cx -> fp16 [2048][4096] ----------------
__global__ __launch_bounds__(256) void k_pre_mfma(
    const bf16* __restrict__ Ah, const bf16* __restrict__ Al,
    const bf16* __restrict__ Bh, const bf16* __restrict__ Bl,
    const float* __restrict__ cx, fp16* __restrict__ pre16) {
  __shared__ __align__(16) char lds[65536];
  char* sAh = lds;
  char* sAl = lds + 16384;
  char* sBh = lds + 32768;
  char* sBl = lds + 49152;
  const int bid = blockIdx.x;
  const int swz = (bid & 7) * 64 + (bid >> 3);  // 512 = 8*64
  const int mt = swz >> 5, nt = swz & 31;
  const int m0 = mt * 128, n0 = nt * 128;
  const int tid = threadIdx.x, w = tid >> 6, lane = tid & 63;
  const int wr = w >> 1, wc = w & 1;

  f32x4 acc[4][4];
  #pragma unroll
  for (int i = 0; i < 4; ++i)
    #pragma unroll
    for (int j = 0; j < 4; ++j) acc[i][j] = (f32x4){0.f, 0.f, 0.f, 0.f};

  int rowc[4], sloc[4];
  #pragma unroll
  for (int i = 0; i < 4; ++i) {
    int c = i * 4 + w;
    rowc[i] = c * 8 + (lane >> 3);
    sloc[i] = (lane & 7) ^ (rowc[i] & 7);
  }

  for (int kk = 0; kk < 4; ++kk) {
    if (kk) __syncthreads();
    const char* gah = (const char*)Ah + kk * 128;
    const char* gal = (const char*)Al + kk * 128;
    const char* gbh = (const char*)Bh + kk * 128;
    const char* gbl = (const char*)Bl + kk * 128;
    #pragma unroll
    for (int i = 0; i < 4; ++i) {
      int c = i * 4 + w;
      load_lds16(gah + (size_t)(m0 + rowc[i]) * 512 + sloc[i] * 16, sAh + c * 1024);
      load_lds16(gal + (size_t)(m0 + rowc[i]) * 512 + sloc[i] * 16, sAl + c * 1024);
      load_lds16(gbh + (size_t)(n0 + rowc[i]) * 512 + sloc[i] * 16, sBh + c * 1024);
      load_lds16(gbl + (size_t)(n0 + rowc[i]) * 512 + sloc[i] * 16, sBl + c * 1024);
    }
    __syncthreads();
    #pragma unroll
    for (int ks = 0; ks < 2; ++ks) {
      bf16x8 avh[4], avl[4], bvh[4], bvl[4];
      #pragma unroll
      for (int f = 0; f < 4; ++f) {
        int ra = wr * 64 + f * 16 + (lane & 15);
        int ca = (ks * 4 + (lane >> 4)) ^ (ra & 7);
        avh[f] = *(const bf16x8*)(sAh + ra * 128 + ca * 16);
        avl[f] = *(const bf16x8*)(sAl + ra * 128 + ca * 16);
        int rb = wc * 64 + f * 16 + (lane & 15);
        int cb = (ks * 4 + (lane >> 4)) ^ (rb & 7);
        bvh[f] = *(const bf16x8*)(sBh + rb * 128 + cb * 16);
        bvl[f] = *(const bf16x8*)(sBl + rb * 128 + cb * 16);
      }
      #pragma unroll
      for (int fm = 0; fm < 4; ++fm)
        #pragma unroll
        for (int fn = 0; fn < 4; ++fn) {
          acc[fm][fn] = __builtin_amdgcn_mfma_f32_16x16x32_bf16(avh[fm], bvh[fn], acc[fm][fn], 0, 0, 0);
          acc[fm][fn] = __builtin_amdgcn_mfma_f32_16x16x32_bf16(avh[fm], bvl[fn], acc[fm][fn], 0, 0, 0);
          acc[fm][fn] = __builtin_amdgcn_mfma_f32_16x16x32_bf16(avl[fm], bvh[fn], acc[fm][fn], 0, 0, 0);
        }
    }
  }

  const int r0o = m0 + wr * 64 + ((lane >> 4) << 2);
  const int c0o = n0 + wc * 64 + (lane & 15);
  #pragma unroll
  for (int fn = 0; fn < 4; ++fn) {
    int colg = c0o + fn * 16;
    #pragma unroll
    for (int fm = 0; fm < 4; ++fm) {
      #pragma unroll
      for (int r = 0; r < 4; ++r) {
        int row = r0o + fm * 16 + r;
        float v = acc[fm][fn][r] + cx[(size_t)(row >> 6) * G + colg];
        pre16[(size_t)row * G + colg] = (fp16)v;
      }
    }
  }
}

// ---------------- recurrence step (MFMA, 256 blocks x 512 thr) ----------------
__global__ __launch_bounds__(512) void k_step3(
    const bf16* __restrict__ Whp_hi, const bf16* __restrict__ Whp_lo,
    const fp16* __restrict__ pre16,
    const bf16* __restrict__ hin_hi, const bf16* __restrict__ hin_lo,
    bf16* __restrict__ hout_hi, bf16* __restrict__ hout_lo,
    float* __restrict__ cst, float* __restrict__ hf32,
    bf16* __restrict__ Hb16, int t) {
  __shared__ float zred[8 * 2 * 64 * 4]; // 16 KB
  __shared__ float zf[32][16];           // 2 KB
  const int jb = blockIdx.x;
  const int tid = threadIdx.x;
  const int w = tid >> 6, lane = tid & 63;

  float pf[4];
  float cprev = 0.f;
  const int gb = tid >> 2, gjo = tid & 3, gj = jb * 4 + gjo;
  if (tid < 128) {
    const size_t pbase = (size_t)(gb * 64 + t) * G + gj;
    #pragma unroll
    for (int g = 0; g < 4; ++g) pf[g] = (float)pre16[pbase + g * 1024];
    cprev = cst[gb * 1024 + gj];
  }

  f32x4 acc[2];
  acc[0] = (f32x4){0.f, 0.f, 0.f, 0.f};
  acc[1] = (f32x4){0.f, 0.f, 0.f, 0.f};
  const int fr = lane & 15, kc = lane >> 4;
  const bf16* bbh = Whp_hi + (size_t)(jb * 16 + fr) * L;
  const bf16* bbl = Whp_lo + (size_t)(jb * 16 + fr) * L;
  #pragma unroll
  for (int kk = 0; kk < 4; ++kk) {
    const int k0 = (w * 4 + kk) * 32 + kc * 8;
    bf16x8 bh = *(const bf16x8*)(bbh + k0);
    bf16x8 bl_ = *(const bf16x8*)(bbl + k0);
    #pragma unroll
    for (int m = 0; m < 2; ++m) {
      const size_t ao = (size_t)(m * 16 + fr) * L + k0;
      bf16x8 ah = *(const bf16x8*)(hin_hi + ao);
      bf16x8 al = *(const bf16x8*)(hin_lo + ao);
      acc[m] = __builtin_amdgcn_mfma_f32_16x16x32_bf16(ah, bh, acc[m], 0, 0, 0);
      acc[m] = __builtin_amdgcn_mfma_f32_16x16x32_bf16(ah, bl_, acc[m], 0, 0, 0);
      acc[m] = __builtin_amdgcn_mfma_f32_16x16x32_bf16(al, bh, acc[m], 0, 0, 0);
    }
  }
  #pragma unroll
  for (int m = 0; m < 2; ++m)
    *(f32x4*)&zred[((w * 2 + m) * 64 + lane) * 4] = acc[m];
  __syncthreads();
  {
    const int b = tid >> 4, c = tid & 15;
    const int lane2 = (((b & 15) >> 2) << 4) | c;
    const int reg = b & 3, m = b >> 4;
    float s = 0.f;
    #pragma unroll
    for (int ww = 0; ww < 8; ++ww)
      s += zred[((ww * 2 + m) * 64 + lane2) * 4 + reg];
    zf[b][c] = s;
  }
  __syncthreads();
  if (tid < 128) {
    float zi = zf[gb][gjo] + pf[0];
    float zff = zf[gb][4 + gjo] + pf[1];
    float zg = zf[gb][8 + gjo] + pf[2];
    float zo = zf[gb][12 + gjo] + pf[3];
    float si = 1.f / (1.f + expf(-zi));
    float sf = 1.f / (1.f + expf(-zff));
    float tg = tanhf(zg);
    float so = 1.f / (1.f + expf(-zo));
    float cn = sf * cprev + si * tg;
    float hn = so * tanhf(cn);
    const int hi_idx = gb * 1024 + gj;
    cst[hi_idx] = cn;
    bf16 hh = (bf16)hn;
    hout_hi[hi_idx] = hh;
    hout_lo[hi_idx] = (bf16)(hn - (float)hh);
    hf32[hi_idx] = hn;
    Hb16[(size_t)(gb * 64 + t) * L + gj] = hh;
  }
}

// ---------------- Wd -> Wdt bf16 (R2-verified) ----------------
__global__ __launch_bounds__(256) void k_wdt(const float* __restrict__ Wd,
                                             bf16* __restrict__ Wdt) {
  __shared__ float s[64][65];
  const int lt = blockIdx.x & 15;
  const int vt = blockIdx.x >> 4;
  const int l0 = lt * 64, v0 = vt * 64;
  const int tid = threadIdx.x;
  const int lv = tid & 63;
  #pragma unroll
  for (int k = 0; k < 16; ++k) {
    int ll = k * 4 + (tid >> 6);
    int v = v0 + lv;
    s[ll][lv] = (v < V) ? Wd[(size_t)(l0 + ll) * V + v] : 0.f;
  }
  __syncthreads();
  const int vv = tid >> 2, lq = tid & 3;
  bf16x8 o0, o1;
  #pragma unroll
  for (int j = 0; j < 8; ++j) {
    o0[j] = (bf16)s[lq * 16 + j][vv];
    o1[j] = (bf16)s[lq * 16 + 8 + j][vv];
  }
  bf16* dst = Wdt + (size_t)(v0 + vv) * 1024 + l0 + lq * 16;
  *(bf16x8*)dst = o0;
  *(bf16x8*)(dst + 8) = o1;
}

// ---------------- logits MFMA GEMM (R2-verified) ----------------
__global__ __launch_bounds__(256) void k_logits_mfma(
    const bf16* __restrict__ Ag, const bf16* __restrict__ Btg,
    const float* __restrict__ bd, float* __restrict__ out) {
  __shared__ __align__(16) char lds[32768];
  char* sA = lds;
  char* sB = lds + 16384;
  const int bid = blockIdx.x;
  const int wg = (bid & 7) * 188 + (bid >> 3);
  const int mt = wg / 94, nt = wg % 94;
  const int m0 = mt * 128, n0 = nt * 128;
  const int tid = threadIdx.x, w = tid >> 6, lane = tid & 63;
  const int wr = w >> 1, wc = w & 1;

  f32x4 acc[4][4];
  #pragma unroll
  for (int i = 0; i < 4; ++i)
    #pragma unroll
    for (int j = 0; j < 4; ++j) acc[i][j] = (f32x4){0.f, 0.f, 0.f, 0.f};

  int rowc[4], sloc[4];
  #pragma unroll
  for (int i = 0; i < 4; ++i) {
    int c = i * 4 + w;
    rowc[i] = c * 8 + (lane >> 3);
    sloc[i] = (lane & 7) ^ (rowc[i] & 7);
  }

  for (int kk = 0; kk < 16; ++kk) {
    if (kk) __syncthreads();
    const char* ga = (const char*)Ag + kk * 128;
    const char* gb = (const char*)Btg + kk * 128;
    #pragma unroll
    for (int i = 0; i < 4; ++i) {
      int c = i * 4 + w;
      load_lds16(ga + (size_t)(m0 + rowc[i]) * 2048 + sloc[i] * 16, sA + c * 1024);
      load_lds16(gb + (size_t)(n0 + rowc[i]) * 2048 + sloc[i] * 16, sB + c * 1024);
    }
    __syncthreads();
    #pragma unroll
    for (int ks = 0; ks < 2; ++ks) {
      bf16x8 av[4], bv[4];
      #pragma unroll
      for (int f = 0; f < 4; ++f) {
        int ra = wr * 64 + f * 16 + (lane & 15);
        int ca = (ks * 4 + (lane >> 4)) ^ (ra & 7);
        av[f] = *(const bf16x8*)(sA + ra * 128 + ca * 16);
        int rb = wc * 64 + f * 16 + (lane & 15);
        int cb = (ks * 4 + (lane >> 4)) ^ (rb & 7);
        bv[f] = *(const bf16x8*)(sB + rb * 128 + cb * 16);
      }
      #pragma unroll
      for (int fm = 0; fm < 4; ++fm)
        #pragma unroll
        for (int fn = 0; fn < 4; ++fn)
          acc[fm][fn] = __builtin_amdgcn_mfma_f32_16x16x32_bf16(
              av[fm], bv[fn], acc[fm][fn], 0, 0, 0);
    }
  }

  const int r0o = m0 + wr * 64 + ((lane >> 4) << 2);
  const int c0o = n0 + wc * 64 + (lane & 15);
  #pragma unroll
  for (int fn = 0; fn < 4; ++fn) {
    int colg = c0o + fn * 16;
    if (colg < V) {
      float bv = bd[colg];
      #pragma unroll
      for (int fm = 0; fm < 4; ++fm) {
        #pragma unroll
        for (int r = 0; r < 4; ++r)
          out[(size_t)(r0o + fm * 16 + r) * V + colg] = acc[fm][fn][r] + bv;
      }
    }
  }
}

// ---------------- row softmax (R2-verified) ----------------
__global__ __launch_bounds__(256) void k_softmax(float* __restrict__ logits) {
  __shared__ float srow[V];
  __shared__ float sred[4];
  float* row = logits + (size_t)blockIdx.x * V;
  const int tid = threadIdx.x;
  const float4* rv = (const float4*)row;
  float4* sv = (float4*)srow;
  float m = -3.4e38f;
  for (int i = tid; i < 3000; i += 256) {
    float4 x = rv[i];
    sv[i] = x;
    m = fmaxf(fmaxf(m, fmaxf(x.x, x.y)), fmaxf(x.z, x.w));
  }
  #pragma unroll
  for (int off = 32; off; off >>= 1) m = fmaxf(m, __shfl_xor(m, off));
  if ((tid & 63) == 0) sred[tid >> 6] = m;
  __syncthreads();
  const float M = fmaxf(fmaxf(sred[0], sred[1]), fmaxf(sred[2], sred[3]));
  float s = 0.f;
  for (int i = tid; i < 3000; i += 256) {
    float4 x = sv[i];
    x.x = __expf(x.x - M); x.y = __expf(x.y - M);
    x.z = __expf(x.z - M); x.w = __expf(x.w - M);
    sv[i] = x;
    s += x.x + x.y + x.z + x.w;
  }
  #pragma unroll
  for (int off = 32; off; off >>= 1) s += __shfl_xor(s, off);
  __syncthreads();
  if ((tid & 63) == 0) sred[tid >> 6] = s;
  __syncthreads();
  const float inv = 1.f / (sred[0] + sred[1] + sred[2] + sred[3]);
  float4* ov = (float4*)row;
  for (int i = tid; i < 3000; i += 256) {
    float4 x = sv[i];
    x.x *= inv; x.y *= inv; x.z *= inv; x.w *= inv;
    ov[i] = x;
  }
}

__global__ void k_finalize(const float* __restrict__ hf32, const float* __restrict__ cst,
                           float* __restrict__ oh, float* __restrict__ oc) {
  int i = blockIdx.x * 256 + threadIdx.x;
  if (i < B * L) {
    oh[i] = hf32[i];
    oc[i] = cst[i];
  }
}

// ---------------- launch ----------------

extern "C" void kernel_launch(void* const* d_in, const int* in_sizes, int n_in,
                              void* d_out, int out_size, void* d_ws, size_t ws_size,
                              hipStream_t stream) {
  const int*   targets = (const int*)d_in[0];
  const float* options = (const float*)d_in[1];
  const float* h0      = (const float*)d_in[2];
  const float* c0      = (const float*)d_in[3];
  const float* emb     = (const float*)d_in[4];
  const float* W2      = (const float*)d_in[7];
  const float* Va      = (const float*)d_in[9];
  const float* Wx      = (const float*)d_in[11];
  const float* Wh      = (const float*)d_in[12];
  const float* bl      = (const float*)d_in[13];
  const float* Wd      = (const float*)d_in[14];
  const float* bd      = (const float*)d_in[15];

  float* out      = (float*)d_out;
  float* out_h    = out + N_PROBS;
  float* out_c    = out_h + (size_t)B * L;
  float* out_attn = out_c + (size_t)B * L;

  // ---- workspace layout (bytes), total 41,037,824 B = 39.1 MiB ----
  char* wsb = (char*)d_ws;
  float* v2     = (float*)(wsb);               //       0 + 4 KB
  float* wat    = (float*)(wsb + 4096);        //    4096 + 8 KB
  float* ctx    = (float*)(wsb + 12288);       //   12288 + 128 KB
  float* cx     = (float*)(wsb + 143360);      //  143360 + 512 KiB (32*4096*4)
  float* cst    = (float*)(wsb + 667648);      //  667648 + 128 KB
  bf16*  hA_hi  = (bf16*)(wsb + 798720);       // + 64 KB
  bf16*  hA_lo  = (bf16*)(wsb + 864256);       // + 64 KB
  bf16*  hB_hi  = (bf16*)(wsb + 929792);       // + 64 KB
  bf16*  hB_lo  = (bf16*)(wsb + 995328);       // + 64 KB
  float* hf32   = (float*)(wsb + 1060864);     // + 128 KB -> 1191936
  // X region (6 MB): Eg/Wx2t during precompute; Hb16 (4 MB) aliases after pre-GEMM
  bf16*  Eg_hi  = (bf16*)(wsb + 1191936);      // + 1 MB
  bf16*  Eg_lo  = (bf16*)(wsb + 2240512);      // + 1 MB
  bf16*  Wx2t_hi= (bf16*)(wsb + 3289088);      // + 2 MB
  bf16*  Wx2t_lo= (bf16*)(wsb + 5386240);      // + 2 MB -> 7483392
  bf16*  Hb16   = (bf16*)(wsb + 1191936);      // alias X base, 4 MB (post pre-GEMM)
  bf16*  Whp_hi = (bf16*)(wsb + 7483392);      // 4096*1024*2 = 8 MB
  bf16*  Whp_lo = (bf16*)(wsb + 15872000);     // 8 MB -> 24260608
  fp16*  pre16  = (fp16*)(wsb + 24260608);     // 2048*4096*2 = 16 MB -> 41037824  [THE FIX]
  float* cxp    = (float*)(wsb + 24260608);    // alias pre16 (4 MB, used pre-GEMM only)
  bf16*  Wdt    = (bf16*)(wsb + 7483392);      // alias Whp+pre16 (24.6 MB, post-steps)

  // attention (h-independent)
  k_v2<<<256, 256, 0, stream>>>(W2, Va, v2);
  k_score<<<512, 256, 0, stream>>>(options, v2, wat);
  k_attn_softmax<<<8, 256, 0, stream>>>(wat, out_attn);
  k_context<<<128, 256, 0, stream>>>(options, wat, ctx);
  k_cx_part<<<512, 256, 0, stream>>>(ctx, Wx, cxp);
  k_cx_reduce<<<512, 256, 0, stream>>>(cxp, bl, cx);

  // transforms
  k_eg<<<2048, 256, 0, stream>>>(targets, emb, Eg_hi, Eg_lo);
  k_wx2t<<<256, 256, 0, stream>>>(Wx, Wx2t_hi, Wx2t_lo);
  k_whp<<<1024, 256, 0, stream>>>(Wh, Whp_hi, Whp_lo);

  // pre = Eg @ Wx2 + cx  (fp16, correctly sized)
  k_pre_mfma<<<512, 256, 0, stream>>>(Eg_hi, Eg_lo, Wx2t_hi, Wx2t_lo, cx, pre16);
  k_h0split<<<128, 256, 0, stream>>>(h0, c0, hA_hi, hA_lo, cst, hf32);

  // recurrence
  for (int t = 0; t < T; ++t) {
    const bf16* ih = (t & 1) ? hB_hi : hA_hi;
    const bf16* il = (t & 1) ? hB_lo : hA_lo;
    bf16* oh2 = (t & 1) ? hA_hi : hB_hi;
    bf16* ol2 = (t & 1) ? hA_lo : hB_lo;
    k_step3<<<256, 512, 0, stream>>>(Whp_hi, Whp_lo, pre16,
                                     ih, il, oh2, ol2, cst, hf32, Hb16, t);
  }

  // logits + softmax + finalize
  k_wdt<<<188 * 16, 256, 0, stream>>>(Wd, Wdt);
  k_logits_mfma<<<1504, 256, 0, stream>>>(Hb16, Wdt, bd, out);
  k_softmax<<<B * T, 256, 0, stream>>>(out);
  k_finalize<<<128, 256, 0, stream>>>(hf32, cst, out_h, out_c);
}